// Round 1
// baseline (517.913 us; speedup 1.0000x reference)
//
#include <hip/hip_runtime.h>
#include <cmath>

#define NN 2048
#define DD 64

#define EPSF 0.1f
#define K2 14.426950408889634f   /* (1/eps) * log2(e) */
#define LN2F 0.6931471805599453f

// online logsumexp combine in base-2 domain: (M,S) <- (M,S) ++ (m,s)
__device__ __forceinline__ void lse_combine(float& M, float& S, float m, float s) {
    float mn = fmaxf(M, m);
    S = S * exp2f(M - mn) + s * exp2f(m - mn);
    M = mn;
}

__device__ __forceinline__ bool sink_done(const float* __restrict__ err, int it) {
    for (int k = 0; k < it; ++k)
        if (err[k] < 0.1f) return true;
    return false;
}

// ---------------------------------------------------------------------------
// Kernel 1: C[i][j] = sum_d (x[i][d]-y[j][d])^2 ; also zero-init ws + cost
// grid (32, 16), block 256.  Tile: 128 rows of x, 64 rows of y.
// ---------------------------------------------------------------------------
__global__ __launch_bounds__(256) void sink_cost_matrix(
        const float* __restrict__ x, const float* __restrict__ y,
        float* __restrict__ Cout, float* __restrict__ wsz, float* __restrict__ cost) {
    __shared__ float xs[128][65];
    __shared__ float ys[64][65];
    int tid = threadIdx.x;
    int bj = blockIdx.x, bi = blockIdx.y;

    if (bi == 0 && bj == 0) {
        // u (2048) + v (2048) + err (16 slots, only 10 used)
        for (int k = tid; k < 2048 + 2048 + 16; k += 256) wsz[k] = 0.f;
        if (tid == 0) cost[0] = 0.f;
    }

    const float4* x4 = (const float4*)x;
    const float4* y4 = (const float4*)y;
    for (int q = tid; q < 128 * 16; q += 256) {
        int r = q >> 4, dq = q & 15;
        float4 val = x4[(size_t)(bi * 128 + r) * 16 + dq];
        xs[r][dq * 4 + 0] = val.x; xs[r][dq * 4 + 1] = val.y;
        xs[r][dq * 4 + 2] = val.z; xs[r][dq * 4 + 3] = val.w;
    }
    for (int q = tid; q < 64 * 16; q += 256) {
        int r = q >> 4, dq = q & 15;
        float4 val = y4[(size_t)(bj * 64 + r) * 16 + dq];
        ys[r][dq * 4 + 0] = val.x; ys[r][dq * 4 + 1] = val.y;
        ys[r][dq * 4 + 2] = val.z; ys[r][dq * 4 + 3] = val.w;
    }
    __syncthreads();

    int tx = tid & 15, ty = tid >> 4;
    float acc[8][4];
#pragma unroll
    for (int ii = 0; ii < 8; ++ii)
#pragma unroll
        for (int jj = 0; jj < 4; ++jj) acc[ii][jj] = 0.f;

#pragma unroll 4
    for (int dd = 0; dd < 64; ++dd) {
        float xv[8], yv[4];
#pragma unroll
        for (int ii = 0; ii < 8; ++ii) xv[ii] = xs[ty + 16 * ii][dd];
#pragma unroll
        for (int jj = 0; jj < 4; ++jj) yv[jj] = ys[tx + 16 * jj][dd];
#pragma unroll
        for (int ii = 0; ii < 8; ++ii)
#pragma unroll
            for (int jj = 0; jj < 4; ++jj) {
                float d = xv[ii] - yv[jj];
                acc[ii][jj] = fmaf(d, d, acc[ii][jj]);
            }
    }

#pragma unroll
    for (int ii = 0; ii < 8; ++ii)
#pragma unroll
        for (int jj = 0; jj < 4; ++jj) {
            int gi = bi * 128 + ty + 16 * ii;
            int gj = bj * 64 + tx + 16 * jj;
            Cout[(size_t)gi * NN + gj] = acc[ii][jj];
        }
}

// ---------------------------------------------------------------------------
// Kernel 2 (per iteration): u_i = eps*(log_mu - LSE_j((-C_ij+v_j)/eps))
// grid 2048 (one row per block), block 256. Accumulates err[it].
// ---------------------------------------------------------------------------
__global__ __launch_bounds__(256) void sink_row(
        const float* __restrict__ C, float* __restrict__ u,
        const float* __restrict__ v, float* __restrict__ err,
        int it, float log_mu) {
    if (sink_done(err, it)) return;
    int i = blockIdx.x;
    int tid = threadIdx.x;
    const float* row = C + (size_t)i * NN;

    float m = -INFINITY, s = 0.f;
    for (int j = tid; j < NN; j += 256) {
        float a = (v[j] - row[j]) * K2;
        lse_combine(m, s, a, 1.0f);
    }
    // wave64 butterfly reduce
#pragma unroll
    for (int off = 1; off < 64; off <<= 1) {
        float mo = __shfl_xor(m, off);
        float so = __shfl_xor(s, off);
        lse_combine(m, s, mo, so);
    }
    __shared__ float sm[4], ss[4];
    if ((tid & 63) == 0) { sm[tid >> 6] = m; ss[tid >> 6] = s; }
    __syncthreads();
    if (tid == 0) {
        float M = sm[0], S = ss[0];
#pragma unroll
        for (int w = 1; w < 4; ++w) lse_combine(M, S, sm[w], ss[w]);
        float L = LN2F * (M + log2f(S));     // natural-log LSE
        float un = EPSF * (log_mu - L);
        atomicAdd(&err[it], fabsf(un - u[i]));
        u[i] = un;
    }
}

// ---------------------------------------------------------------------------
// Kernel 3 (per iteration): column-LSE partials.
// grid (8, 32): blockIdx.x = 256-col tile, blockIdx.y = 64-row chunk.
// Coalesced row-major reads; one column per thread.
// ---------------------------------------------------------------------------
__global__ __launch_bounds__(256) void sink_colpart(
        const float* __restrict__ C, const float* __restrict__ u,
        float* __restrict__ pm, float* __restrict__ ps,
        const float* __restrict__ err, int it) {
    if (sink_done(err, it)) return;
    int j = blockIdx.x * 256 + threadIdx.x;
    int r0 = blockIdx.y * 64;
    float m = -INFINITY, s = 0.f;
    for (int r = r0; r < r0 + 64; ++r) {
        float a = (u[r] - C[(size_t)r * NN + j]) * K2;
        lse_combine(m, s, a, 1.0f);
    }
    pm[(size_t)blockIdx.y * NN + j] = m;
    ps[(size_t)blockIdx.y * NN + j] = s;
}

// ---------------------------------------------------------------------------
// Kernel 4 (per iteration): finish column LSE -> v_j
// grid 8, block 256 (one column per thread, 32 partials each)
// ---------------------------------------------------------------------------
__global__ __launch_bounds__(256) void sink_colfin(
        const float* __restrict__ pm, const float* __restrict__ ps,
        float* __restrict__ v, const float* __restrict__ err,
        int it, float log_nu) {
    if (sink_done(err, it)) return;
    int j = blockIdx.x * 256 + threadIdx.x;
    float M = -INFINITY, S = 0.f;
    for (int c = 0; c < 32; ++c)
        lse_combine(M, S, pm[(size_t)c * NN + j], ps[(size_t)c * NN + j]);
    v[j] = EPSF * (log_nu - LN2F * (M + log2f(S)));
}

// ---------------------------------------------------------------------------
// Kernel 5: pi = exp((-C+u+v)/eps), cost = sum(pi*C)
// grid 2048 (one row per block), block 256.
// ---------------------------------------------------------------------------
__global__ __launch_bounds__(256) void sink_pi(
        const float* __restrict__ C, const float* __restrict__ u,
        const float* __restrict__ v, float* __restrict__ pi,
        float* __restrict__ cost) {
    int i = blockIdx.x;
    int tid = threadIdx.x;
    const float* row = C + (size_t)i * NN;
    float ui = u[i];
    float local = 0.f;
    for (int j = tid; j < NN; j += 256) {
        float c = row[j];
        float p = exp2f((ui + v[j] - c) * K2);
        pi[(size_t)i * NN + j] = p;
        local = fmaf(p, c, local);
    }
#pragma unroll
    for (int off = 1; off < 64; off <<= 1) local += __shfl_xor(local, off);
    __shared__ float sl[4];
    if ((tid & 63) == 0) sl[tid >> 6] = local;
    __syncthreads();
    if (tid == 0) atomicAdd(cost, sl[0] + sl[1] + sl[2] + sl[3]);
}

extern "C" void kernel_launch(void* const* d_in, const int* in_sizes, int n_in,
                              void* d_out, int out_size, void* d_ws, size_t ws_size,
                              hipStream_t stream) {
    const float* x = (const float*)d_in[0];
    const float* y = (const float*)d_in[1];
    float* out  = (float*)d_out;
    float* cost = out;                       // [0]
    float* pi   = out + 1;                   // [1 .. 1+2048*2048)
    float* C    = out + 1 + (size_t)NN * NN; // [.. 1+2*2048*2048)

    float* ws  = (float*)d_ws;
    float* u   = ws;            // 2048
    float* v   = ws + 2048;     // 2048
    float* err = ws + 4096;     // 10 (+pad)

    // stash column-LSE partials in the pi region (unused until sink_pi)
    float* pm = pi;
    float* ps = pi + 32 * (size_t)NN;

    float log_mu = (float)log(1.0 / 2048.0 + 1e-8); // n == m -> log_nu == log_mu

    sink_cost_matrix<<<dim3(32, 16), 256, 0, stream>>>(x, y, C, ws, cost);
    for (int it = 0; it < 10; ++it) {
        sink_row<<<2048, 256, 0, stream>>>(C, u, v, err, it, log_mu);
        sink_colpart<<<dim3(8, 32), 256, 0, stream>>>(C, u, pm, ps, err, it);
        sink_colfin<<<8, 256, 0, stream>>>(pm, ps, v, err, it, log_mu);
    }
    sink_pi<<<2048, 256, 0, stream>>>(C, u, v, pi, cost);
}

// Round 2
// 202.992 us; speedup vs baseline: 2.5514x; 2.5514x over previous
//
#include <hip/hip_runtime.h>
#include <cmath>

#define NN 2048

#define EPSF 0.1f
#define K2 14.426950408889634f   /* (1/eps) * log2(e) */
#define LN2F 0.6931471805599453f

// ws layout (floats)
#define U_OFF   0
#define V_OFF   2048
#define ERR_OFF 4096
#define DU_OFF  4112
#define CWS_OFF 6160
#define PM_OFF  (6160 + 2048*2048)
#define PS_OFF  (PM_OFF + 128*2048)

__device__ __forceinline__ float fexp2(float x) { return __builtin_amdgcn_exp2f(x); }
__device__ __forceinline__ float flog2(float x) { return __builtin_amdgcn_logf(x); }

// online logsumexp combine in base-2 domain: (M,S) <- (M,S) ++ (m,s)
__device__ __forceinline__ void lse_combine(float& M, float& S, float m, float s) {
    float mn = fmaxf(M, m);
    S = S * fexp2(M - mn) + s * fexp2(m - mn);
    M = mn;
}

__device__ __forceinline__ bool sink_done(const float* __restrict__ err, int it) {
    for (int k = 0; k < it; ++k)
        if (err[k] < 0.1f) return true;
    return false;
}

// ---------------------------------------------------------------------------
// Kernel 1: C[i][j] = sum_d (x[i][d]-y[j][d])^2 -> Cout (output) + Cws (aligned)
// Also zero-inits u/v/err/du and cost. grid (32, 16), block 256.
// ---------------------------------------------------------------------------
__global__ __launch_bounds__(256) void sink_cost_matrix(
        const float* __restrict__ x, const float* __restrict__ y,
        float* __restrict__ Cout, float* __restrict__ Cws,
        float* __restrict__ wsz, float* __restrict__ cost) {
    __shared__ float xs[128][65];
    __shared__ float ys[64][65];
    int tid = threadIdx.x;
    int bj = blockIdx.x, bi = blockIdx.y;

    if (bi == 0 && bj == 0) {
        // u(2048) + v(2048) + err(16) + du(2048)
        for (int k = tid; k < 2048 + 2048 + 16 + 2048; k += 256) wsz[k] = 0.f;
        if (tid == 0) cost[0] = 0.f;
    }

    const float4* x4 = (const float4*)x;
    const float4* y4 = (const float4*)y;
    for (int q = tid; q < 128 * 16; q += 256) {
        int r = q >> 4, dq = q & 15;
        float4 val = x4[(size_t)(bi * 128 + r) * 16 + dq];
        xs[r][dq * 4 + 0] = val.x; xs[r][dq * 4 + 1] = val.y;
        xs[r][dq * 4 + 2] = val.z; xs[r][dq * 4 + 3] = val.w;
    }
    for (int q = tid; q < 64 * 16; q += 256) {
        int r = q >> 4, dq = q & 15;
        float4 val = y4[(size_t)(bj * 64 + r) * 16 + dq];
        ys[r][dq * 4 + 0] = val.x; ys[r][dq * 4 + 1] = val.y;
        ys[r][dq * 4 + 2] = val.z; ys[r][dq * 4 + 3] = val.w;
    }
    __syncthreads();

    int tx = tid & 15, ty = tid >> 4;
    float acc[8][4];
#pragma unroll
    for (int ii = 0; ii < 8; ++ii)
#pragma unroll
        for (int jj = 0; jj < 4; ++jj) acc[ii][jj] = 0.f;

#pragma unroll 4
    for (int dd = 0; dd < 64; ++dd) {
        float xv[8], yv[4];
#pragma unroll
        for (int ii = 0; ii < 8; ++ii) xv[ii] = xs[ty + 16 * ii][dd];
#pragma unroll
        for (int jj = 0; jj < 4; ++jj) yv[jj] = ys[tx + 16 * jj][dd];
#pragma unroll
        for (int ii = 0; ii < 8; ++ii)
#pragma unroll
            for (int jj = 0; jj < 4; ++jj) {
                float d = xv[ii] - yv[jj];
                acc[ii][jj] = fmaf(d, d, acc[ii][jj]);
            }
    }

#pragma unroll
    for (int ii = 0; ii < 8; ++ii)
#pragma unroll
        for (int jj = 0; jj < 4; ++jj) {
            int gi = bi * 128 + ty + 16 * ii;
            int gj = bj * 64 + tx + 16 * jj;
            Cout[(size_t)gi * NN + gj] = acc[ii][jj];
            Cws [(size_t)gi * NN + gj] = acc[ii][jj];
        }
}

// ---------------------------------------------------------------------------
// Kernel 2 (per iter): u_i = eps*(log_mu - LSE_j((v_j - C_ij)/eps)); du_i=|Δ|
// grid 2048 (one row per block), block 256. float4 loads, 4 LSE streams.
// ---------------------------------------------------------------------------
__global__ __launch_bounds__(256) void sink_row(
        const float* __restrict__ Cws, float* __restrict__ u,
        const float* __restrict__ v, const float* __restrict__ err,
        float* __restrict__ du, int it, float log_mu) {
    if (sink_done(err, it)) return;
    int i = blockIdx.x;
    int tid = threadIdx.x;
    const float4* row4 = (const float4*)(Cws + (size_t)i * NN);
    const float4* v4 = (const float4*)v;

    float m0 = -INFINITY, m1 = -INFINITY, m2 = -INFINITY, m3 = -INFINITY;
    float s0 = 0.f, s1 = 0.f, s2 = 0.f, s3 = 0.f;
    for (int k = tid; k < NN / 4; k += 256) {
        float4 c = row4[k];
        float4 vv = v4[k];
        lse_combine(m0, s0, (vv.x - c.x) * K2, 1.0f);
        lse_combine(m1, s1, (vv.y - c.y) * K2, 1.0f);
        lse_combine(m2, s2, (vv.z - c.z) * K2, 1.0f);
        lse_combine(m3, s3, (vv.w - c.w) * K2, 1.0f);
    }
    lse_combine(m0, s0, m1, s1);
    lse_combine(m2, s2, m3, s3);
    lse_combine(m0, s0, m2, s2);
#pragma unroll
    for (int off = 1; off < 64; off <<= 1) {
        float mo = __shfl_xor(m0, off);
        float so = __shfl_xor(s0, off);
        lse_combine(m0, s0, mo, so);
    }
    __shared__ float sm[4], ss[4];
    if ((tid & 63) == 0) { sm[tid >> 6] = m0; ss[tid >> 6] = s0; }
    __syncthreads();
    if (tid == 0) {
        float M = sm[0], S = ss[0];
#pragma unroll
        for (int w = 1; w < 4; ++w) lse_combine(M, S, sm[w], ss[w]);
        float un = EPSF * (log_mu - LN2F * (M + flog2(S)));
        du[i] = fabsf(un - u[i]);
        u[i] = un;
    }
}

// ---------------------------------------------------------------------------
// Kernel 3 (per iter): column-LSE partials over 16-row chunks.
// grid (2, 128): x = 1024-col tile, y = 16-row chunk. 4 cols/thread (float4).
// ---------------------------------------------------------------------------
__global__ __launch_bounds__(256) void sink_colpart(
        const float* __restrict__ Cws, const float* __restrict__ u,
        float* __restrict__ pm, float* __restrict__ ps,
        const float* __restrict__ err, int it) {
    if (sink_done(err, it)) return;
    int tid = threadIdx.x;
    int j0 = blockIdx.x * 1024 + tid * 4;
    int r0 = blockIdx.y * 16;
    float m0 = -INFINITY, m1 = -INFINITY, m2 = -INFINITY, m3 = -INFINITY;
    float s0 = 0.f, s1 = 0.f, s2 = 0.f, s3 = 0.f;
#pragma unroll 4
    for (int r = r0; r < r0 + 16; ++r) {
        float ur = u[r];
        float4 c = *(const float4*)(Cws + (size_t)r * NN + j0);
        lse_combine(m0, s0, (ur - c.x) * K2, 1.0f);
        lse_combine(m1, s1, (ur - c.y) * K2, 1.0f);
        lse_combine(m2, s2, (ur - c.z) * K2, 1.0f);
        lse_combine(m3, s3, (ur - c.w) * K2, 1.0f);
    }
    *(float4*)(pm + (size_t)blockIdx.y * NN + j0) = make_float4(m0, m1, m2, m3);
    *(float4*)(ps + (size_t)blockIdx.y * NN + j0) = make_float4(s0, s1, s2, s3);
}

// ---------------------------------------------------------------------------
// Kernel 4 (per iter): finish col LSE -> v_j ; block 0 also reduces du -> err[it]
// grid 256, block 256: 8 cols/block, 32-thread team per col (4 partials each).
// ---------------------------------------------------------------------------
__global__ __launch_bounds__(256) void sink_colfin(
        const float* __restrict__ pm, const float* __restrict__ ps,
        float* __restrict__ v, const float* __restrict__ du,
        float* __restrict__ err, int it, float log_nu) {
    if (sink_done(err, it)) return;
    int tid = threadIdx.x;
    int col = blockIdx.x * 8 + (tid >> 5);
    int l = tid & 31;
    float M = -INFINITY, S = 0.f;
#pragma unroll
    for (int k = 0; k < 4; ++k) {
        int c = l * 4 + k;
        lse_combine(M, S, pm[(size_t)c * NN + col], ps[(size_t)c * NN + col]);
    }
#pragma unroll
    for (int off = 1; off < 32; off <<= 1) {
        float mo = __shfl_xor(M, off);
        float so = __shfl_xor(S, off);
        lse_combine(M, S, mo, so);
    }
    if (l == 0) v[col] = EPSF * (log_nu - LN2F * (M + flog2(S)));

    if (blockIdx.x == 0) {
        float t = 0.f;
        for (int k = tid; k < NN; k += 256) t += du[k];
#pragma unroll
        for (int off = 1; off < 64; off <<= 1) t += __shfl_xor(t, off);
        __shared__ float sl[4];
        if ((tid & 63) == 0) sl[tid >> 6] = t;
        __syncthreads();
        if (tid == 0) err[it] = sl[0] + sl[1] + sl[2] + sl[3];
    }
}

// ---------------------------------------------------------------------------
// Kernel 5: pi = exp((-C+u+v)/eps), cost = sum(pi*C)
// grid 256 (8 rows per block), block 256. One atomic per block.
// ---------------------------------------------------------------------------
__global__ __launch_bounds__(256) void sink_pi(
        const float* __restrict__ Cws, const float* __restrict__ u,
        const float* __restrict__ v, float* __restrict__ pi,
        float* __restrict__ cost) {
    int tid = threadIdx.x;
    const float4* v4 = (const float4*)v;
    float local = 0.f;
    for (int rr = 0; rr < 8; ++rr) {
        int i = blockIdx.x * 8 + rr;
        float ui = u[i];
        const float4* row4 = (const float4*)(Cws + (size_t)i * NN);
        float* prow = pi + (size_t)i * NN;
        for (int k = tid; k < NN / 4; k += 256) {
            float4 c = row4[k];
            float4 vv = v4[k];
            float p0 = fexp2((ui + vv.x - c.x) * K2);
            float p1 = fexp2((ui + vv.y - c.y) * K2);
            float p2 = fexp2((ui + vv.z - c.z) * K2);
            float p3 = fexp2((ui + vv.w - c.w) * K2);
            prow[4 * k + 0] = p0;
            prow[4 * k + 1] = p1;
            prow[4 * k + 2] = p2;
            prow[4 * k + 3] = p3;
            local = fmaf(p0, c.x, local);
            local = fmaf(p1, c.y, local);
            local = fmaf(p2, c.z, local);
            local = fmaf(p3, c.w, local);
        }
    }
#pragma unroll
    for (int off = 1; off < 64; off <<= 1) local += __shfl_xor(local, off);
    __shared__ float sl[4];
    if ((tid & 63) == 0) sl[tid >> 6] = local;
    __syncthreads();
    if (tid == 0) atomicAdd(cost, sl[0] + sl[1] + sl[2] + sl[3]);
}

extern "C" void kernel_launch(void* const* d_in, const int* in_sizes, int n_in,
                              void* d_out, int out_size, void* d_ws, size_t ws_size,
                              hipStream_t stream) {
    const float* x = (const float*)d_in[0];
    const float* y = (const float*)d_in[1];
    float* out  = (float*)d_out;
    float* cost = out;                       // [0]
    float* pi   = out + 1;                   // [1 .. 1+2048*2048)
    float* Cout = out + 1 + (size_t)NN * NN; // [.. 1+2*2048*2048)

    float* ws  = (float*)d_ws;
    float* u   = ws + U_OFF;
    float* v   = ws + V_OFF;
    float* err = ws + ERR_OFF;
    float* du  = ws + DU_OFF;
    float* Cws = ws + CWS_OFF;
    float* pm  = ws + PM_OFF;
    float* ps  = ws + PS_OFF;

    float log_mu = (float)log(1.0 / 2048.0 + 1e-8); // n == m -> log_nu == log_mu

    sink_cost_matrix<<<dim3(32, 16), 256, 0, stream>>>(x, y, Cout, Cws, ws, cost);
    for (int it = 0; it < 10; ++it) {
        sink_row<<<2048, 256, 0, stream>>>(Cws, u, v, err, du, it, log_mu);
        sink_colpart<<<dim3(2, 128), 256, 0, stream>>>(Cws, u, pm, ps, err, it);
        sink_colfin<<<256, 256, 0, stream>>>(pm, ps, v, du, err, it, log_mu);
    }
    sink_pi<<<256, 256, 0, stream>>>(Cws, u, v, pi, cost);
}